// Round 7
// baseline (281.545 us; speedup 1.0000x reference)
//
#include <hip/hip_runtime.h>
#include <hip/hip_bf16.h>
#include <cstdint>

#define TOKENS 8192
#define DIN 1024
#define DOUT 1024
#define NE 8

typedef __bf16 bf16;
typedef __attribute__((ext_vector_type(8))) __bf16 bf16x8;
typedef __attribute__((ext_vector_type(4))) float floatx4;
typedef __attribute__((ext_vector_type(2))) float floatx2;

// async global->LDS, 16B per lane. LDS dest must be wave-uniform base + lane*16.
__device__ __forceinline__ void async16(const void* gptr, void* lptr) {
  __builtin_amdgcn_global_load_lds(
      (const __attribute__((address_space(1))) void*)gptr,
      (__attribute__((address_space(3))) void*)lptr,
      16, 0, 0);
}

// scale a bf16x8 A-fragment (one row, 8 k-values) by a scalar in f32, round
// back to bf16. Pairs should compile to shl/and + 2 mul + v_cvt_pk_bf16_f32.
__device__ __forceinline__ bf16x8 scale_frag(bf16x8 a, float s) {
  union { bf16x8 v; uint32_t u[4]; } in, out;
  in.v = a;
#pragma unroll
  for (int j = 0; j < 4; ++j) {
    const float lo = __uint_as_float(in.u[j] << 16) * s;
    const float hi = __uint_as_float(in.u[j] & 0xffff0000u) * s;
    union { bf16 b; uint16_t q; } c0, c1;
    c0.b = (bf16)lo;
    c1.b = (bf16)hi;
    out.u[j] = (uint32_t)c0.q | ((uint32_t)c1.q << 16);
  }
  return out.v;
}

// ---------------------------------------------------------------------------
// Fused prep: blocks [0,2048) = gate softmax + x->bf16; blocks [2048,4096) =
// W[e][i][o] fp32 -> Wt[e][o][i] bf16 transpose.
// ---------------------------------------------------------------------------
__global__ __launch_bounds__(256) void prep_kernel(
    const float* __restrict__ x, const float* __restrict__ gw,
    const float* __restrict__ gb, float* __restrict__ g,
    bf16* __restrict__ xb, const float* __restrict__ w,
    bf16* __restrict__ wt) {
  __shared__ float tile[64][65];

  if (blockIdx.x < 2048) {
    const int lane = threadIdx.x & 63;
    const int wave = threadIdx.x >> 6;
    const int t = blockIdx.x * 4 + wave;
    const float* xr = x + (size_t)t * DIN;
    bf16* xbr = xb + (size_t)t * DIN;

    float acc[NE];
#pragma unroll
    for (int e = 0; e < NE; ++e) acc[e] = 0.f;

#pragma unroll
    for (int it = 0; it < 8; ++it) {
      const int i = it * 128 + lane * 2;
      const floatx2 xv = *(const floatx2*)(xr + i);
      union { bf16 b[2]; uint32_t u; } cv;
      cv.b[0] = (bf16)xv[0]; cv.b[1] = (bf16)xv[1];
      *(uint32_t*)(xbr + i) = cv.u;
      const floatx4 w00 = *(const floatx4*)(gw + (size_t)i * NE);
      const floatx4 w01 = *(const floatx4*)(gw + (size_t)i * NE + 4);
      const floatx4 w10 = *(const floatx4*)(gw + (size_t)(i + 1) * NE);
      const floatx4 w11 = *(const floatx4*)(gw + (size_t)(i + 1) * NE + 4);
#pragma unroll
      for (int e = 0; e < 4; ++e) {
        acc[e]     += xv[0] * w00[e] + xv[1] * w10[e];
        acc[e + 4] += xv[0] * w01[e] + xv[1] * w11[e];
      }
    }
#pragma unroll
    for (int e = 0; e < NE; ++e) {
#pragma unroll
      for (int off = 32; off > 0; off >>= 1)
        acc[e] += __shfl_xor(acc[e], off, 64);
    }
    float lg[NE];
    float mx = -3.0e38f;
#pragma unroll
    for (int e = 0; e < NE; ++e) { lg[e] = acc[e] + gb[e]; mx = fmaxf(mx, lg[e]); }
    float s = 0.f;
#pragma unroll
    for (int e = 0; e < NE; ++e) { lg[e] = __expf(lg[e] - mx); s += lg[e]; }
    const float inv = 1.f / s;
    if (lane == 0) {
      floatx4 o0, o1;
#pragma unroll
      for (int e = 0; e < 4; ++e) { o0[e] = lg[e] * inv; o1[e] = lg[e + 4] * inv; }
      *(floatx4*)(g + (size_t)t * NE) = o0;
      *(floatx4*)(g + (size_t)t * NE + 4) = o1;
    }
  } else {
    const int b = blockIdx.x - 2048;
    const int e = b >> 8;
    const int i0 = ((b >> 4) & 15) * 64;
    const int o0 = (b & 15) * 64;
    const int tid = threadIdx.x;
    const int c4 = (tid & 15) * 4;
    const int r = tid >> 4;

    const float* src = w + ((size_t)e * DIN + i0) * DOUT + o0;
#pragma unroll
    for (int rr = r; rr < 64; rr += 16) {
      const floatx4 v = *(const floatx4*)(src + (size_t)rr * DOUT + c4);
      tile[rr][c4] = v[0]; tile[rr][c4 + 1] = v[1];
      tile[rr][c4 + 2] = v[2]; tile[rr][c4 + 3] = v[3];
    }
    __syncthreads();
    bf16* dst = wt + ((size_t)e * DOUT + o0) * DIN + i0;
#pragma unroll
    for (int rr = r; rr < 64; rr += 16) {
      union { bf16 b[4]; uint64_t u; } cv;
#pragma unroll
      for (int j = 0; j < 4; ++j) cv.b[j] = (bf16)tile[c4 + j][rr];
      *(uint64_t*)(dst + (size_t)rr * DIN + c4) = cv.u;
    }
  }
}

// ---------------------------------------------------------------------------
// Fused MoE GEMM, R7: K-window outer / expert INNER.
// Per BK=64 window: stage As once, read 8 A-fragments to registers once;
// per expert stream only Bs and fold the gate into the A-fragments
// (avs = bf16(g[row,e] * av); A-frag = one row -> scalar per lane per frag),
// accumulating into a SINGLE accF via the MFMA C-chain. Cuts A LDS reads
// and A staging 8x vs the e-outer structure. Swizzle = R4's (measured 0
// conflicts). g cached in 32 VGPRs, loaded once.
// ---------------------------------------------------------------------------
__global__ __launch_bounds__(256, 2) void moe_gemm(
    const bf16* __restrict__ xb, const bf16* __restrict__ wt,
    const float* __restrict__ g, float* __restrict__ out) {
  __shared__ __align__(16) bf16 As[128 * 64];  // 16KB
  __shared__ __align__(16) bf16 Bs[128 * 64];  // 16KB

  const int tid = threadIdx.x;
  const int bm = blockIdx.x >> 3;
  const int bn = blockIdx.x & 7;
  const int lane = tid & 63;
  const int wave = tid >> 6;
  const int wm = wave >> 1, wn = wave & 1;
  const int lr = lane & 15, lq = lane >> 4;

  // staging (R4 geometry, measured conflict-free): pass j covers rows
  // 32j..32j+31; unit u=tid+256j -> row=u>>3, pos=u&7, col=(pos^(row&7))*8.
  const int srow = tid >> 3;                                  // 0..31
  const int scol = (((tid & 7) ^ (srow & 7)) << 3);           // swizzled col

  const bf16* agp = xb + ((size_t)(bm * 128 + srow)) * DIN + scol;
  const bf16* bgp = wt + ((size_t)(bn * 128 + srow)) * DIN + scol;
  bf16* const alp = As + tid * 8;
  bf16* const blp = Bs + tid * 8;

  const int kx = lr & 7;
  const int tok0 = bm * 128 + wm * 64;

  // gate cache: g[row(im,lr), e] for all 8 experts, 4 im -> 32 VGPRs.
  float gr[NE][4];
#pragma unroll
  for (int e = 0; e < NE; ++e)
#pragma unroll
    for (int im = 0; im < 4; ++im)
      gr[e][im] = g[(size_t)(tok0 + im * 16 + lr) * NE + e];

  const floatx4 fzero = {0.f, 0.f, 0.f, 0.f};
  floatx4 accF[4][4];
#pragma unroll
  for (int im = 0; im < 4; ++im)
#pragma unroll
    for (int in = 0; in < 4; ++in) accF[im][in] = fzero;

  for (int k0 = 0; k0 < DIN; k0 += 64) {
    __syncthreads();  // protect As/Bs from previous window's readers
#pragma unroll
    for (int j = 0; j < 4; ++j) {
      async16(agp + k0 + (size_t)(32 * j) * DIN, alp + j * 2048);
      async16(bgp + k0 + (size_t)(32 * j) * DIN, blp + j * 2048);  // e=0
    }
    __syncthreads();  // drain

    // read A-fragments ONCE per window (reused across all 8 experts)
    bf16x8 av[2][4];
#pragma unroll
    for (int h = 0; h < 2; ++h)
#pragma unroll
      for (int im = 0; im < 4; ++im)
        av[h][im] = *(const bf16x8*)(
            As + (wm * 64 + im * 16 + lr) * 64 + (((h * 4 + lq) ^ kx) << 3));

#pragma unroll
    for (int e = 0; e < NE; ++e) {
#pragma unroll
      for (int h = 0; h < 2; ++h) {
        const int kg = ((h * 4 + lq) ^ kx) << 3;
        bf16x8 avs[4];
#pragma unroll
        for (int im = 0; im < 4; ++im)
          avs[im] = scale_frag(av[h][im], gr[e][im]);
        bf16x8 bv[4];
#pragma unroll
        for (int in = 0; in < 4; ++in)
          bv[in] = *(const bf16x8*)(Bs + (wn * 64 + in * 16 + lr) * 64 + kg);
#pragma unroll
        for (int im = 0; im < 4; ++im)
#pragma unroll
          for (int in = 0; in < 4; ++in)
            accF[im][in] = __builtin_amdgcn_mfma_f32_16x16x32_bf16(
                avs[im], bv[in], accF[im][in], 0, 0, 0);
      }
      if (e < NE - 1) {
        __syncthreads();  // Bs[e] reads done
#pragma unroll
        for (int j = 0; j < 4; ++j)
          async16(bgp + ((size_t)(e + 1) << 20) + k0 + (size_t)(32 * j) * DIN,
                  blp + j * 2048);
        __syncthreads();  // drain
      }
    }
  }

#pragma unroll
  for (int im = 0; im < 4; ++im)
#pragma unroll
    for (int in = 0; in < 4; ++in) {
      const int col = bn * 128 + wn * 64 + in * 16 + lr;
#pragma unroll
      for (int r = 0; r < 4; ++r)
        out[(size_t)(tok0 + im * 16 + lq * 4 + r) * DOUT + col] =
            accF[im][in][r];
    }
}

// ---------------------------------------------------------------------------
extern "C" void kernel_launch(void* const* d_in, const int* in_sizes, int n_in,
                              void* d_out, int out_size, void* d_ws,
                              size_t ws_size, hipStream_t stream) {
  const float* x  = (const float*)d_in[0];
  const float* gw = (const float*)d_in[1];
  const float* gb = (const float*)d_in[2];
  const float* w  = (const float*)d_in[3];
  float* out = (float*)d_out;

  char* ws = (char*)d_ws;
  float* g  = (float*)ws;
  bf16* xb  = (bf16*)(ws + 262144);
  bf16* wt  = (bf16*)(ws + 262144 + (size_t)TOKENS * DIN * 2);

  prep_kernel<<<4096, 256, 0, stream>>>(x, gw, gb, g, xb, w, wt);
  moe_gemm<<<512, 256, 0, stream>>>(xb, wt, g, out);
}